// Round 13
// baseline (728.845 us; speedup 1.0000x reference)
//
#include <hip/hip_runtime.h>
#include <hip/hip_bf16.h>
#include <cstdint>

#define NN 30000
#define EE 480000
#define GG 64

typedef __attribute__((ext_vector_type(8))) short bf16x8;
typedef __attribute__((ext_vector_type(4))) float float4v;
typedef __attribute__((ext_vector_type(2))) float f32x2;
typedef __attribute__((ext_vector_type(4))) unsigned short ushort4v;

static __device__ inline unsigned short f2bf(float f) {
    unsigned u = __float_as_uint(f);
    unsigned r = (u + 0x7fff + ((u >> 16) & 1)) >> 16;   // RNE
    return (unsigned short)r;
}
static __device__ inline float bf2f(unsigned short u) {
    return __uint_as_float(((unsigned)u) << 16);
}

// ---------------------------------------------------------------- CSR build
__global__ void count_deg_k(const int* __restrict__ ei, int* __restrict__ deg) {
    int e = blockIdx.x * 256 + threadIdx.x;
    if (e < EE) atomicAdd(&deg[ei[EE + e]], 1);
}

__global__ __launch_bounds__(1024) void scan_excl_k(const int* __restrict__ deg,
                                                    int* __restrict__ basep) {
    constexpr int CH = (NN + 1024) / 1024 + 1;   // 30
    __shared__ int buf[1024];
    int t = threadIdx.x;
    int b0 = t * CH;
    int loc[CH];
    int s = 0;
#pragma unroll
    for (int i = 0; i < CH; i++) {
        int idx = b0 + i;
        int v = (idx < NN) ? deg[idx] : 0;
        loc[i] = s;
        s += v;
    }
    buf[t] = s;
    __syncthreads();
    for (int off = 1; off < 1024; off <<= 1) {
        int tv = (t >= off) ? buf[t - off] : 0;
        __syncthreads();
        buf[t] += tv;
        __syncthreads();
    }
    int base = (t > 0) ? buf[t - 1] : 0;
#pragma unroll
    for (int i = 0; i < CH; i++) {
        int idx = b0 + i;
        if (idx <= NN) basep[idx] = base + loc[i];
    }
}

__global__ void fill_csr_k(const int* __restrict__ ei, const float* __restrict__ ea,
                           const int* __restrict__ basep, int* __restrict__ cnt,
                           int* __restrict__ csrc, float* __restrict__ cea) {
    int e = blockIdx.x * 256 + threadIdx.x;
    if (e < EE) {
        int d = ei[EE + e];
        int pos = basep[d] + atomicAdd(&cnt[d], 1);
        csrc[pos] = ei[e];
        cea[pos] = ea[e];
    }
}

// batch is sorted: group start offsets
__global__ void gbound_k(const int* __restrict__ batch, int* __restrict__ gstart) {
    int i = blockIdx.x * 256 + threadIdx.x;
    if (i >= NN) return;
    int cur = batch[i];
    if (i == 0) {
        for (int g = 0; g <= cur; ++g) gstart[g] = 0;
    } else {
        int prev = batch[i - 1];
        for (int g = prev + 1; g <= cur; ++g) gstart[g] = i;
    }
    if (i == NN - 1) {
        for (int g = cur + 1; g <= GG; ++g) gstart[g] = NN;
    }
}

// ---------------------------------------------------------------- prep
struct PrepDesc { const float* src; void* dst; int rows; int cols; int blk0; int mode; };
#define NDESC 25
struct PrepArgs { PrepDesc d[NDESC]; };

__global__ __launch_bounds__(256) void prep_k(PrepArgs args) {
    int b = blockIdx.x;
    PrepDesc dd = args.d[0];
#pragma unroll
    for (int i = 1; i < NDESC; i++)
        if (b >= args.d[i].blk0) dd = args.d[i];
    int rel = b - dd.blk0;
    int total = dd.rows * dd.cols;
    int base = rel * 1024 + threadIdx.x;
    if (dd.mode == 0) {
        unsigned short* dst = (unsigned short*)dd.dst;
        for (int j = 0; j < 4; j++) {
            int i = base + j * 256;
            if (i < total) dst[i] = f2bf(dd.src[i]);
        }
    } else if (dd.mode == 1) {
        unsigned short* dst = (unsigned short*)dd.dst;
        for (int j = 0; j < 4; j++) {
            int i = base + j * 256;
            if (i < total) {
                int n = i / dd.rows, k = i - n * dd.rows;
                dst[i] = f2bf(dd.src[(size_t)k * dd.cols + n]);
            }
        }
    } else {
        float* dst = (float*)dd.dst;
        for (int j = 0; j < 4; j++) {
            int i = base + j * 256;
            if (i < total) dst[i] = dd.src[i];
        }
    }
}

// ---------------------------------------------------------------- bf16 MFMA GEMM
// C[M][N] = A[M][K] @ Wt[N][K]^T + bias.  128x128 tile, BK=32.
// 3-buffer LDS pipeline, counted vmcnt (prefetch distance 2, never drained).
// Fused fp8 pack: cols [N/4, 3N/4) (the K|V slice) also stored to KV8.
__global__ __launch_bounds__(256) void gemm_bf16_k(
    const unsigned short* __restrict__ A, const unsigned short* __restrict__ Wt,
    const float* __restrict__ bias, unsigned short* __restrict__ C,
    unsigned char* __restrict__ KV8,
    int M, int K, int N) {
    __shared__ unsigned short As[3][4096];   // 8KB per buf
    __shared__ unsigned short Bs[3][4096];
    int tid = threadIdx.x;
    int lane = tid & 63, wid = tid >> 6;
    int wm = wid >> 1, wn = wid & 1;

    // bijective XCD-aware remap
    int gx = gridDim.x;
    int T = gx * gridDim.y;
    int lid = blockIdx.y * gx + blockIdx.x;
    int qq = T >> 3, rr = T & 7;
    int xcd = lid & 7, pos = lid >> 3;
    int tile = ((xcd < rr) ? xcd * (qq + 1) : rr * (qq + 1) + (xcd - rr) * qq) + pos;
    int by = tile / gx, bx = tile - by * gx;
    int row0 = by * 128, n0 = bx * 128;

    float4v acc[4][4];
#pragma unroll
    for (int i = 0; i < 4; i++)
#pragma unroll
        for (int j = 0; j < 4; j++) acc[i][j] = (float4v)0.f;

    auto stage = [&](int buf, int t) {
        int k0 = t << 5;
#pragma unroll
        for (int i = 0; i < 2; ++i) {
            int chunkbase = i * 256 + wid * 64;          // wave-uniform
            int chunk = chunkbase + lane;
            int r = chunk & 127, kc = chunk >> 7;
            int rowA = row0 + r; if (rowA >= M) rowA = M - 1;
            const unsigned short* ga = A + (size_t)rowA * K + (k0 + kc * 8);
            __builtin_amdgcn_global_load_lds(
                (const __attribute__((address_space(1))) void*)ga,
                (__attribute__((address_space(3))) void*)(As[buf] + (size_t)chunkbase * 8),
                16, 0, 0);
            const unsigned short* gb = Wt + (size_t)(n0 + r) * K + (k0 + kc * 8);
            __builtin_amdgcn_global_load_lds(
                (const __attribute__((address_space(1))) void*)gb,
                (__attribute__((address_space(3))) void*)(Bs[buf] + (size_t)chunkbase * 8),
                16, 0, 0);
        }
    };

    int NT = K >> 5;          // >= 8 for all layers
    stage(0, 0);
    stage(1, 1);

    for (int t = 0; t < NT; ++t) {
        int b = t % 3;
        // wait for buffer t's 4 loads (leave t+1's in flight), then sync.
        if (t + 1 < NT) asm volatile("s_waitcnt vmcnt(4)" ::: "memory");
        else            asm volatile("s_waitcnt vmcnt(0)" ::: "memory");
        __syncthreads();   // all waves' buf-t loads landed; all waves done reading buf (t-1)%3
        if (t + 2 < NT) stage((t + 2) % 3, t + 2);

        bf16x8 af[4], bfr[4];
#pragma unroll
        for (int mi = 0; mi < 4; mi++)
            af[mi] = *(const bf16x8*)(As[b] + ((lane >> 4) * 128 + wm * 64 + mi * 16 + (lane & 15)) * 8);
#pragma unroll
        for (int ni = 0; ni < 4; ni++)
            bfr[ni] = *(const bf16x8*)(Bs[b] + ((lane >> 4) * 128 + wn * 64 + ni * 16 + (lane & 15)) * 8);
#pragma unroll
        for (int mi = 0; mi < 4; mi++)
#pragma unroll
            for (int ni = 0; ni < 4; ni++)
                acc[mi][ni] = __builtin_amdgcn_mfma_f32_16x16x32_bf16(
                    bfr[ni], af[mi], acc[mi][ni], 0, 0, 0);
    }

    // epilogue: bias + bf16 store; K|V cols [N/4, 3N/4) also packed to fp8 KV8.
    int kvlo = N >> 2, kvhi = 3 * (N >> 2);
    float4v bias4[4];
#pragma unroll
    for (int ni = 0; ni < 4; ni++)
        bias4[ni] = *(const float4v*)&bias[n0 + wn * 64 + ni * 16 + (lane >> 4) * 4];
#pragma unroll
    for (int mi = 0; mi < 4; mi++) {
        int row = row0 + wm * 64 + mi * 16 + (lane & 15);
        if (row < M) {
#pragma unroll
            for (int ni = 0; ni < 4; ni++) {
                int colb = n0 + wn * 64 + ni * 16 + (lane >> 4) * 4;
                float v0 = acc[mi][ni][0] + bias4[ni][0];
                float v1 = acc[mi][ni][1] + bias4[ni][1];
                float v2 = acc[mi][ni][2] + bias4[ni][2];
                float v3 = acc[mi][ni][3] + bias4[ni][3];
                ushort4v pk;
                pk[0] = f2bf(v0); pk[1] = f2bf(v1); pk[2] = f2bf(v2); pk[3] = f2bf(v3);
                *(ushort4v*)(C + (size_t)row * N + colb) = pk;
                if (colb >= kvlo && colb < kvhi) {
                    unsigned q = 0;
                    q = __builtin_amdgcn_cvt_pk_fp8_f32(v0, v1, q, false);
                    q = __builtin_amdgcn_cvt_pk_fp8_f32(v2, v3, q, true);
                    *(unsigned*)(KV8 + (size_t)row * (N >> 1) + (colb - kvlo)) = q;
                }
            }
        }
    }
}

// ---------------------------------------------------------------- aggregate
template <int VEC> struct RawVec;
template <> struct RawVec<2> { using T = unsigned; };
template <> struct RawVec<4> { using T = uint2; };
template <> struct RawVec<8> { using T = uint4; };

// fp8 raw: VEC bytes per lane
template <int VEC> struct Raw8;
template <> struct Raw8<2> { using T = unsigned short; };
template <> struct Raw8<4> { using T = unsigned; };
template <> struct Raw8<8> { using T = uint2; };

static __device__ inline void unpackr(unsigned v, float (&r)[2]) {
    r[0] = __uint_as_float(v << 16); r[1] = __uint_as_float(v & 0xffff0000u);
}
static __device__ inline void unpackr(uint2 v, float (&r)[4]) {
    r[0] = __uint_as_float(v.x << 16); r[1] = __uint_as_float(v.x & 0xffff0000u);
    r[2] = __uint_as_float(v.y << 16); r[3] = __uint_as_float(v.y & 0xffff0000u);
}
static __device__ inline void unpackr(uint4 v, float (&r)[8]) {
    r[0] = __uint_as_float(v.x << 16); r[1] = __uint_as_float(v.x & 0xffff0000u);
    r[2] = __uint_as_float(v.y << 16); r[3] = __uint_as_float(v.y & 0xffff0000u);
    r[4] = __uint_as_float(v.z << 16); r[5] = __uint_as_float(v.z & 0xffff0000u);
    r[6] = __uint_as_float(v.w << 16); r[7] = __uint_as_float(v.w & 0xffff0000u);
}

// fp8 e4m3 -> f32 via HW cvt
static __device__ inline void unpackf8(unsigned short v, float (&r)[2]) {
    f32x2 a = __builtin_amdgcn_cvt_pk_f32_fp8((unsigned)v, false);
    r[0] = a[0]; r[1] = a[1];
}
static __device__ inline void unpackf8(unsigned v, float (&r)[4]) {
    f32x2 a0 = __builtin_amdgcn_cvt_pk_f32_fp8(v, false);
    f32x2 a1 = __builtin_amdgcn_cvt_pk_f32_fp8(v, true);
    r[0] = a0[0]; r[1] = a0[1]; r[2] = a1[0]; r[3] = a1[1];
}
static __device__ inline void unpackf8(uint2 v, float (&r)[8]) {
    f32x2 a0 = __builtin_amdgcn_cvt_pk_f32_fp8(v.x, false);
    f32x2 a1 = __builtin_amdgcn_cvt_pk_f32_fp8(v.x, true);
    f32x2 a2 = __builtin_amdgcn_cvt_pk_f32_fp8(v.y, false);
    f32x2 a3 = __builtin_amdgcn_cvt_pk_f32_fp8(v.y, true);
    r[0] = a0[0]; r[1] = a0[1]; r[2] = a1[0]; r[3] = a1[1];
    r[4] = a2[0]; r[5] = a2[1]; r[6] = a3[0]; r[7] = a3[1];
}

template <int VEC>
__device__ inline void loadbf(const unsigned short* __restrict__ p, float (&r)[VEC]) {
    typename RawVec<VEC>::T v = *(const typename RawVec<VEC>::T*)p;
    unpackr(v, r);
}
template <int VEC>
__device__ inline void loadf32(const float* __restrict__ p, float (&r)[VEC]) {
    if constexpr (VEC == 2) {
        float2 t = *reinterpret_cast<const float2*>(p);
        r[0] = t.x; r[1] = t.y;
    } else {
#pragma unroll
        for (int i = 0; i < VEC; i += 4) {
            float4 t = *reinterpret_cast<const float4*>(p + i);
            r[i] = t.x; r[i + 1] = t.y; r[i + 2] = t.z; r[i + 3] = t.w;
        }
    }
}
template <int VEC>
__device__ inline void storebf(unsigned short* __restrict__ p, const float (&r)[VEC]) {
    unsigned w[VEC / 2];
#pragma unroll
    for (int i = 0; i < VEC / 2; i++)
        w[i] = (unsigned)f2bf(r[2 * i]) | ((unsigned)f2bf(r[2 * i + 1]) << 16);
    if constexpr (VEC == 2) *(unsigned*)p = w[0];
    else if constexpr (VEC == 4) *(uint2*)p = make_uint2(w[0], w[1]);
    else *(uint4*)p = make_uint4(w[0], w[1], w[2], w[3]);
}

// One wave per node. Q,S from bf16 QKVS; K,V gathered from packed fp8 KV8.
template <int H, int D, bool RELU>
__global__ __launch_bounds__(256) void aggregate_k(
    const unsigned short* __restrict__ QKVS, int SR,
    const unsigned char* __restrict__ KV8,
    const float* __restrict__ ew,
    const int* __restrict__ rowptr, const int* __restrict__ csrc,
    const float* __restrict__ cea, unsigned short* __restrict__ Hout) {
    constexpr int F = H * D;
    constexpr int VEC = F / 64;
    constexpr int L = 64 / H;
    using RawT = typename Raw8<VEC>::T;
    int lane = threadIdx.x & 63;
    int node = blockIdx.x * 4 + (threadIdx.x >> 6);
    if (node >= NN) return;

    const unsigned short* qrow = QKVS + (size_t)node * SR;
    float q[VEC], ewv[VEC], acc[VEC];
    loadbf<VEC>(qrow + lane * VEC, q);
    loadf32<VEC>(ew + lane * VEC, ewv);
#pragma unroll
    for (int i = 0; i < VEC; i++) acc[i] = 0.f;

    float den = 0.f;
    const float isd = rsqrtf((float)D);
    int beg = rowptr[node], end = rowptr[node + 1];

    for (int cb = beg; cb < end; cb += 64) {
        int cnt = min(end - cb, 64);
        int gi = cb + lane;
        int sidx = (gi < end) ? csrc[gi] : 0;        // coalesced: 64 indices
        float sea = (gi < end) ? cea[gi] : 0.f;      // coalesced: 64 edge attrs

        RawT k0r, k1r, k2r, k3r, v0r, v1r, v2r, v3r;
        float e0 = 0.f, e1 = 0.f, e2 = 0.f, e3 = 0.f;
        auto fetch = [&](int t, RawT& kr, RawT& vr, float& ea) {
            int s = __shfl(sidx, t, 64);
            ea = __shfl(sea, t, 64);
            const unsigned char* b = KV8 + (size_t)s * (2 * F) + lane * VEC;
            kr = *(const RawT*)b;
            vr = *(const RawT*)(b + F);
        };
        auto process = [&](RawT kr, RawT vr, float ea) {
            float kv[VEC], vv[VEC], t[VEC];
            unpackf8(kr, kv);
            unpackf8(vr, vv);
            float p = 0.f;
#pragma unroll
            for (int i = 0; i < VEC; i++) { t[i] = ea * ewv[i]; p += q[i] * (kv[i] + t[i]); }
#pragma unroll
            for (int off = 1; off < L; off <<= 1) p += __shfl_xor(p, off, 64);
            float w = __expf(fminf(p * isd, 30.f));
            den += w;
#pragma unroll
            for (int i = 0; i < VEC; i++) acc[i] += w * (vv[i] + t[i]);
        };

        if (cnt > 0) fetch(0, k0r, v0r, e0);
        if (cnt > 1) fetch(1, k1r, v1r, e1);
        if (cnt > 2) fetch(2, k2r, v2r, e2);
        if (cnt > 3) fetch(3, k3r, v3r, e3);

        for (int t = 0; t < cnt; t += 4) {
            process(k0r, v0r, e0);
            if (t + 4 < cnt) fetch(t + 4, k0r, v0r, e0);
            if (t + 1 < cnt) {
                process(k1r, v1r, e1);
                if (t + 5 < cnt) fetch(t + 5, k1r, v1r, e1);
            }
            if (t + 2 < cnt) {
                process(k2r, v2r, e2);
                if (t + 6 < cnt) fetch(t + 6, k2r, v2r, e2);
            }
            if (t + 3 < cnt) {
                process(k3r, v3r, e3);
                if (t + 7 < cnt) fetch(t + 7, k3r, v3r, e3);
            }
        }
    }

    float rden = (den > 0.f) ? 1.f / den : 0.f;
    float sv[VEC];
    loadbf<VEC>(qrow + 3 * F + lane * VEC, sv);
    float o[VEC];
#pragma unroll
    for (int i = 0; i < VEC; i++) {
        float v = acc[i] * rden + sv[i];
        o[i] = RELU ? fmaxf(v, 0.f) : v;
    }
    storebf<VEC>(Hout + (size_t)node * F + lane * VEC, o);
}

// ---------------------------------------------------------------- pool+head (fused)
__global__ __launch_bounds__(256) void pool_head_k(
    const unsigned short* __restrict__ h3, const int* __restrict__ gstart,
    const float* __restrict__ lw, const float* __restrict__ lb,
    float* __restrict__ out) {
    __shared__ float part[256];
    __shared__ float pooled[128];
    int g = blockIdx.x;
    int beg = gstart[g], end = gstart[g + 1];
    int d = threadIdx.x & 127, half = threadIdx.x >> 7;
    float s = 0.f;
    for (int node = beg + half; node < end; node += 2)
        s += bf2f(h3[(size_t)node * 128 + d]);
    part[threadIdx.x] = s;
    __syncthreads();
    if (threadIdx.x < 128) {
        float cnt = fmaxf((float)(end - beg), 1.0f);
        pooled[threadIdx.x] = (part[threadIdx.x] + part[threadIdx.x + 128]) / cnt;
    }
    __syncthreads();
    if (threadIdx.x < 13) {
        float acc = lb[threadIdx.x];
        for (int dd = 0; dd < 128; ++dd)
            acc += pooled[dd] * lw[dd * 13 + threadIdx.x];
        out[g * 13 + threadIdx.x] = acc;
    }
}

__global__ void ws_fail_k(float* __restrict__ out, int n) {
    int i = blockIdx.x * 256 + threadIdx.x;
    if (i < n) out[i] = -12345.0f;
}

// ---------------------------------------------------------------- launch
extern "C" void kernel_launch(void* const* d_in, const int* in_sizes, int n_in,
                              void* d_out, int out_size, void* d_ws, size_t ws_size,
                              hipStream_t stream) {
    const float* x   = (const float*)d_in[0];
    const int*   ei  = (const int*)d_in[1];
    const float* ea  = (const float*)d_in[2];
    const int*   bat = (const int*)d_in[3];
    const float* W1[4] = {(const float*)d_in[4], (const float*)d_in[6], (const float*)d_in[8], (const float*)d_in[11]};
    const float* B1[4] = {(const float*)d_in[5], (const float*)d_in[7], (const float*)d_in[9], (const float*)d_in[12]};
    const float* e1w = (const float*)d_in[10];
    const float* W2[4] = {(const float*)d_in[13], (const float*)d_in[15], (const float*)d_in[17], (const float*)d_in[20]};
    const float* B2[4] = {(const float*)d_in[14], (const float*)d_in[16], (const float*)d_in[18], (const float*)d_in[21]};
    const float* e2w = (const float*)d_in[19];
    const float* W3[4] = {(const float*)d_in[22], (const float*)d_in[24], (const float*)d_in[26], (const float*)d_in[29]};
    const float* B3[4] = {(const float*)d_in[23], (const float*)d_in[25], (const float*)d_in[27], (const float*)d_in[30]};
    const float* e3w = (const float*)d_in[28];
    const float* lw  = (const float*)d_in[31];
    const float* lb  = (const float*)d_in[32];

    char* wsb = (char*)d_ws;
    size_t off = 0;
    auto alloc_b = [&](size_t bytes) {
        void* p = wsb + off;
        off += (bytes + 255) & ~(size_t)255;
        return p;
    };
    unsigned short* xb   = (unsigned short*)alloc_b((size_t)NN * 256 * 2);
    unsigned short* Wc1  = (unsigned short*)alloc_b((size_t)2048 * 256 * 2);
    float*          bc1  = (float*)alloc_b(2048 * 4);
    unsigned short* Wc2  = (unsigned short*)alloc_b((size_t)1024 * 512 * 2);
    float*          bc2  = (float*)alloc_b(1024 * 4);
    unsigned short* Wc3  = (unsigned short*)alloc_b((size_t)512 * 256 * 2);
    float*          bc3  = (float*)alloc_b(512 * 4);
    unsigned short* QKVS = (unsigned short*)alloc_b((size_t)NN * 2048 * 2);
    unsigned char*  KV8  = (unsigned char*)alloc_b((size_t)NN * 1024);   // max 2F = 1024 bytes/row
    unsigned short* H1   = (unsigned short*)alloc_b((size_t)NN * 512 * 2);
    unsigned short* H2   = (unsigned short*)alloc_b((size_t)NN * 256 * 2);
    unsigned short* H3   = (unsigned short*)alloc_b((size_t)NN * 128 * 2);
    int*   basep  = (int*)alloc_b((NN + 1) * 4);
    int*   csrc   = (int*)alloc_b((size_t)EE * 4);
    float* cea    = (float*)alloc_b((size_t)EE * 4);
    int*   gstart = (int*)alloc_b((GG + 1) * 4);
    size_t zstart = off;
    int*   deg    = (int*)alloc_b(NN * 4);
    int*   cnt    = (int*)alloc_b(NN * 4);
    size_t zbytes = off - zstart;

    if (ws_size < off) {
        ws_fail_k<<<(out_size + 255) / 256, 256, 0, stream>>>((float*)d_out, out_size);
        return;
    }

    hipMemsetAsync(wsb + zstart, 0, zbytes, stream);

    PrepArgs pa;
    int blk = 0, di = 0;
    auto add = [&](const float* src, void* dst, int rows, int cols, int mode) {
        pa.d[di].src = src; pa.d[di].dst = dst;
        pa.d[di].rows = rows; pa.d[di].cols = cols;
        pa.d[di].mode = mode; pa.d[di].blk0 = blk;
        blk += (rows * cols + 1023) / 1024;
        di++;
    };
    add(x, xb, NN * 256, 1, 0);
    for (int s = 0; s < 4; s++) add(W1[s], Wc1 + (size_t)s * 512 * 256, 256, 512, 1);
    for (int s = 0; s < 4; s++) add(B1[s], bc1 + s * 512, 512, 1, 2);
    for (int s = 0; s < 4; s++) add(W2[s], Wc2 + (size_t)s * 256 * 512, 512, 256, 1);
    for (int s = 0; s < 4; s++) add(B2[s], bc2 + s * 256, 256, 1, 2);
    for (int s = 0; s < 4; s++) add(W3[s], Wc3 + (size_t)s * 128 * 256, 256, 128, 1);
    for (int s = 0; s < 4; s++) add(B3[s], bc3 + s * 128, 128, 1, 2);
    prep_k<<<blk, 256, 0, stream>>>(pa);

    int eblocks = (EE + 255) / 256;
    count_deg_k<<<eblocks, 256, 0, stream>>>(ei, deg);
    scan_excl_k<<<1, 1024, 0, stream>>>(deg, basep);
    fill_csr_k<<<eblocks, 256, 0, stream>>>(ei, ea, basep, cnt, csrc, cea);
    gbound_k<<<(NN + 255) / 256, 256, 0, stream>>>(bat, gstart);

    int mblocks = (NN + 127) / 128;
    // ---- layer 1: x[30000,256] -> QKVS[30000,2048] (+ fused fp8 K|V pack)
    gemm_bf16_k<<<dim3(2048 / 128, mblocks), 256, 0, stream>>>(xb, Wc1, bc1, QKVS, KV8, NN, 256, 2048);
    aggregate_k<8, 64, true><<<NN / 4, 256, 0, stream>>>(QKVS, 2048, KV8, e1w, basep, csrc, cea, H1);
    // ---- layer 2: H1[30000,512] -> QKVS[30000,1024]
    gemm_bf16_k<<<dim3(1024 / 128, mblocks), 256, 0, stream>>>(H1, Wc2, bc2, QKVS, KV8, NN, 512, 1024);
    aggregate_k<4, 64, true><<<NN / 4, 256, 0, stream>>>(QKVS, 1024, KV8, e2w, basep, csrc, cea, H2);
    // ---- layer 3: H2[30000,256] -> QKVS[30000,512]
    gemm_bf16_k<<<dim3(512 / 128, mblocks), 256, 0, stream>>>(H2, Wc3, bc3, QKVS, KV8, NN, 256, 512);
    aggregate_k<1, 128, false><<<NN / 4, 256, 0, stream>>>(QKVS, 512, KV8, e3w, basep, csrc, cea, H3);

    // ---- fused pool + head
    pool_head_k<<<GG, 256, 0, stream>>>(H3, gstart, lw, lb, (float*)d_out);
}

// Round 14
// 672.185 us; speedup vs baseline: 1.0843x; 1.0843x over previous
//
#include <hip/hip_runtime.h>
#include <hip/hip_bf16.h>
#include <cstdint>

#define NN 30000
#define EE 480000
#define GG 64

typedef __attribute__((ext_vector_type(8))) short bf16x8;
typedef __attribute__((ext_vector_type(4))) float float4v;
typedef __attribute__((ext_vector_type(2))) float f32x2;
typedef __attribute__((ext_vector_type(4))) unsigned short ushort4v;

static __device__ inline unsigned short f2bf(float f) {
    unsigned u = __float_as_uint(f);
    unsigned r = (u + 0x7fff + ((u >> 16) & 1)) >> 16;   // RNE
    return (unsigned short)r;
}
static __device__ inline float bf2f(unsigned short u) {
    return __uint_as_float(((unsigned)u) << 16);
}

// ---------------------------------------------------------------- CSR build
__global__ void count_deg_k(const int* __restrict__ ei, int* __restrict__ deg) {
    int e = blockIdx.x * 256 + threadIdx.x;
    if (e < EE) atomicAdd(&deg[ei[EE + e]], 1);
}

__global__ __launch_bounds__(1024) void scan_excl_k(const int* __restrict__ deg,
                                                    int* __restrict__ basep) {
    constexpr int CH = (NN + 1024) / 1024 + 1;   // 30
    __shared__ int buf[1024];
    int t = threadIdx.x;
    int b0 = t * CH;
    int loc[CH];
    int s = 0;
#pragma unroll
    for (int i = 0; i < CH; i++) {
        int idx = b0 + i;
        int v = (idx < NN) ? deg[idx] : 0;
        loc[i] = s;
        s += v;
    }
    buf[t] = s;
    __syncthreads();
    for (int off = 1; off < 1024; off <<= 1) {
        int tv = (t >= off) ? buf[t - off] : 0;
        __syncthreads();
        buf[t] += tv;
        __syncthreads();
    }
    int base = (t > 0) ? buf[t - 1] : 0;
#pragma unroll
    for (int i = 0; i < CH; i++) {
        int idx = b0 + i;
        if (idx <= NN) basep[idx] = base + loc[i];
    }
}

__global__ void fill_csr_k(const int* __restrict__ ei, const float* __restrict__ ea,
                           const int* __restrict__ basep, int* __restrict__ cnt,
                           int* __restrict__ csrc, float* __restrict__ cea) {
    int e = blockIdx.x * 256 + threadIdx.x;
    if (e < EE) {
        int d = ei[EE + e];
        int pos = basep[d] + atomicAdd(&cnt[d], 1);
        csrc[pos] = ei[e];
        cea[pos] = ea[e];
    }
}

// batch is sorted: group start offsets
__global__ void gbound_k(const int* __restrict__ batch, int* __restrict__ gstart) {
    int i = blockIdx.x * 256 + threadIdx.x;
    if (i >= NN) return;
    int cur = batch[i];
    if (i == 0) {
        for (int g = 0; g <= cur; ++g) gstart[g] = 0;
    } else {
        int prev = batch[i - 1];
        for (int g = prev + 1; g <= cur; ++g) gstart[g] = i;
    }
    if (i == NN - 1) {
        for (int g = cur + 1; g <= GG; ++g) gstart[g] = NN;
    }
}

// ---------------------------------------------------------------- prep
struct PrepDesc { const float* src; void* dst; int rows; int cols; int blk0; int mode; };
#define NDESC 25
struct PrepArgs { PrepDesc d[NDESC]; };

__global__ __launch_bounds__(256) void prep_k(PrepArgs args) {
    int b = blockIdx.x;
    PrepDesc dd = args.d[0];
#pragma unroll
    for (int i = 1; i < NDESC; i++)
        if (b >= args.d[i].blk0) dd = args.d[i];
    int rel = b - dd.blk0;
    int total = dd.rows * dd.cols;
    int base = rel * 1024 + threadIdx.x;
    if (dd.mode == 0) {
        unsigned short* dst = (unsigned short*)dd.dst;
        for (int j = 0; j < 4; j++) {
            int i = base + j * 256;
            if (i < total) dst[i] = f2bf(dd.src[i]);
        }
    } else if (dd.mode == 1) {
        unsigned short* dst = (unsigned short*)dd.dst;
        for (int j = 0; j < 4; j++) {
            int i = base + j * 256;
            if (i < total) {
                int n = i / dd.rows, k = i - n * dd.rows;
                dst[i] = f2bf(dd.src[(size_t)k * dd.cols + n]);
            }
        }
    } else {
        float* dst = (float*)dd.dst;
        for (int j = 0; j < 4; j++) {
            int i = base + j * 256;
            if (i < total) dst[i] = dd.src[i];
        }
    }
}

// ---------------------------------------------------------------- bf16 MFMA GEMM
// C[M][N] = A[M][K] @ Wt[N][K]^T + bias.  128x128 tile, BK=32, 2-buffer LDS.
// Epilogue: stage each wave's 64x64 sub-tile in LDS (stride-72 rows), then
// COALESCED 16B-per-lane row-segment stores (fix for the 1.19 TB/s scatter-
// write ceiling seen in r12/r13 counters). Fused fp8 K|V pack from LDS.
__global__ __launch_bounds__(256) void gemm_bf16_k(
    const unsigned short* __restrict__ A, const unsigned short* __restrict__ Wt,
    const float* __restrict__ bias, unsigned short* __restrict__ C,
    unsigned char* __restrict__ KV8,
    int M, int K, int N) {
    __shared__ unsigned short lds[18432];   // 36864 B: pipeline 32KB, staging 36.9KB (aliased)
    int tid = threadIdx.x;
    int lane = tid & 63, wid = tid >> 6;
    int wm = wid >> 1, wn = wid & 1;

    // bijective XCD-aware remap
    int gx = gridDim.x;
    int T = gx * gridDim.y;
    int lid = blockIdx.y * gx + blockIdx.x;
    int qq = T >> 3, rr = T & 7;
    int xcd = lid & 7, pos = lid >> 3;
    int tile = ((xcd < rr) ? xcd * (qq + 1) : rr * (qq + 1) + (xcd - rr) * qq) + pos;
    int by = tile / gx, bx = tile - by * gx;
    int row0 = by * 128, n0 = bx * 128;

    float4v acc[4][4];
#pragma unroll
    for (int i = 0; i < 4; i++)
#pragma unroll
        for (int j = 0; j < 4; j++) acc[i][j] = (float4v)0.f;

    auto As = [&](int b) { return lds + b * 4096; };
    auto Bs = [&](int b) { return lds + 8192 + b * 4096; };

    auto stage = [&](int buf, int t) {
        int k0 = t << 5;
#pragma unroll
        for (int i = 0; i < 2; ++i) {
            int chunkbase = i * 256 + wid * 64;          // wave-uniform
            int chunk = chunkbase + lane;
            int r = chunk & 127, kc = chunk >> 7;
            int rowA = row0 + r; if (rowA >= M) rowA = M - 1;
            const unsigned short* ga = A + (size_t)rowA * K + (k0 + kc * 8);
            __builtin_amdgcn_global_load_lds(
                (const __attribute__((address_space(1))) void*)ga,
                (__attribute__((address_space(3))) void*)(As(buf) + (size_t)chunkbase * 8),
                16, 0, 0);
            const unsigned short* gb = Wt + (size_t)(n0 + r) * K + (k0 + kc * 8);
            __builtin_amdgcn_global_load_lds(
                (const __attribute__((address_space(1))) void*)gb,
                (__attribute__((address_space(3))) void*)(Bs(buf) + (size_t)chunkbase * 8),
                16, 0, 0);
        }
    };

    int NT = K >> 5;
    stage(0, 0);
    asm volatile("s_waitcnt vmcnt(0)" ::: "memory");
    __syncthreads();

    for (int t = 0; t < NT; ++t) {
        int b = t & 1;
        if (t + 1 < NT) stage(b ^ 1, t + 1);
        bf16x8 af[4], bfr[4];
#pragma unroll
        for (int mi = 0; mi < 4; mi++)
            af[mi] = *(const bf16x8*)(As(b) + ((lane >> 4) * 128 + wm * 64 + mi * 16 + (lane & 15)) * 8);
#pragma unroll
        for (int ni = 0; ni < 4; ni++)
            bfr[ni] = *(const bf16x8*)(Bs(b) + ((lane >> 4) * 128 + wn * 64 + ni * 16 + (lane & 15)) * 8);
#pragma unroll
        for (int mi = 0; mi < 4; mi++)
#pragma unroll
            for (int ni = 0; ni < 4; ni++)
                acc[mi][ni] = __builtin_amdgcn_mfma_f32_16x16x32_bf16(
                    bfr[ni], af[mi], acc[mi][ni], 0, 0, 0);
        asm volatile("s_waitcnt vmcnt(0)" ::: "memory");
        __syncthreads();
    }

    // ---- epilogue: bias, stage 64x64 bf16 sub-tile per wave (stride 72), coalesced stores
    // (previous __syncthreads guarantees no wave still reads the pipeline buffers)
    unsigned short* stg = lds + wid * 4608;   // 64 rows x 72 ushorts = 9216 B/wave
    float4v bias4[4];
#pragma unroll
    for (int ni = 0; ni < 4; ni++)
        bias4[ni] = *(const float4v*)&bias[n0 + wn * 64 + ni * 16 + (lane >> 4) * 4];
#pragma unroll
    for (int mi = 0; mi < 4; mi++) {
#pragma unroll
        for (int ni = 0; ni < 4; ni++) {
            ushort4v pk;
#pragma unroll
            for (int r = 0; r < 4; r++) pk[r] = f2bf(acc[mi][ni][r] + bias4[ni][r]);
            *(ushort4v*)(stg + (mi * 16 + (lane & 15)) * 72 + ni * 16 + (lane >> 4) * 4) = pk;
        }
    }
    int rbase = row0 + wm * 64;
    int cbase = n0 + wn * 64;
    // C store: 8 lanes per row-segment (128B), 8 rows per instruction
#pragma unroll
    for (int it = 0; it < 8; ++it) {
        int r = it * 8 + (lane >> 3);
        int row = rbase + r;
        if (row < M) {
            uint4 v = *(const uint4*)(stg + r * 72 + (lane & 7) * 8);
            *(uint4*)(C + (size_t)row * N + cbase + (lane & 7) * 8) = v;
        }
    }
    // fused fp8 K|V pack: cols [N/4, 3N/4) -> KV8[row][col-N/4]
    int kvlo = N >> 2, kvhi = 3 * (N >> 2);
    if (cbase >= kvlo && cbase < kvhi) {
#pragma unroll
        for (int it = 0; it < 8; ++it) {
            int r = it * 8 + (lane >> 3);
            int row = rbase + r;
            if (row < M) {
                const unsigned short* p = stg + r * 72 + (lane & 7) * 8;
                unsigned lo = 0, hi = 0;
                lo = __builtin_amdgcn_cvt_pk_fp8_f32(bf2f(p[0]), bf2f(p[1]), lo, false);
                lo = __builtin_amdgcn_cvt_pk_fp8_f32(bf2f(p[2]), bf2f(p[3]), lo, true);
                hi = __builtin_amdgcn_cvt_pk_fp8_f32(bf2f(p[4]), bf2f(p[5]), hi, false);
                hi = __builtin_amdgcn_cvt_pk_fp8_f32(bf2f(p[6]), bf2f(p[7]), hi, true);
                *(uint2*)(KV8 + (size_t)row * (N >> 1) + (cbase - kvlo) + (lane & 7) * 8) =
                    make_uint2(lo, hi);
            }
        }
    }
}

// ---------------------------------------------------------------- aggregate
template <int VEC> struct RawVec;
template <> struct RawVec<2> { using T = unsigned; };
template <> struct RawVec<4> { using T = uint2; };
template <> struct RawVec<8> { using T = uint4; };

// fp8 raw: VEC bytes per lane
template <int VEC> struct Raw8;
template <> struct Raw8<2> { using T = unsigned short; };
template <> struct Raw8<4> { using T = unsigned; };
template <> struct Raw8<8> { using T = uint2; };

static __device__ inline void unpackr(unsigned v, float (&r)[2]) {
    r[0] = __uint_as_float(v << 16); r[1] = __uint_as_float(v & 0xffff0000u);
}
static __device__ inline void unpackr(uint2 v, float (&r)[4]) {
    r[0] = __uint_as_float(v.x << 16); r[1] = __uint_as_float(v.x & 0xffff0000u);
    r[2] = __uint_as_float(v.y << 16); r[3] = __uint_as_float(v.y & 0xffff0000u);
}
static __device__ inline void unpackr(uint4 v, float (&r)[8]) {
    r[0] = __uint_as_float(v.x << 16); r[1] = __uint_as_float(v.x & 0xffff0000u);
    r[2] = __uint_as_float(v.y << 16); r[3] = __uint_as_float(v.y & 0xffff0000u);
    r[4] = __uint_as_float(v.z << 16); r[5] = __uint_as_float(v.z & 0xffff0000u);
    r[6] = __uint_as_float(v.w << 16); r[7] = __uint_as_float(v.w & 0xffff0000u);
}

// fp8 e4m3 -> f32 via HW cvt
static __device__ inline void unpackf8(unsigned short v, float (&r)[2]) {
    f32x2 a = __builtin_amdgcn_cvt_pk_f32_fp8((unsigned)v, false);
    r[0] = a[0]; r[1] = a[1];
}
static __device__ inline void unpackf8(unsigned v, float (&r)[4]) {
    f32x2 a0 = __builtin_amdgcn_cvt_pk_f32_fp8(v, false);
    f32x2 a1 = __builtin_amdgcn_cvt_pk_f32_fp8(v, true);
    r[0] = a0[0]; r[1] = a0[1]; r[2] = a1[0]; r[3] = a1[1];
}
static __device__ inline void unpackf8(uint2 v, float (&r)[8]) {
    f32x2 a0 = __builtin_amdgcn_cvt_pk_f32_fp8(v.x, false);
    f32x2 a1 = __builtin_amdgcn_cvt_pk_f32_fp8(v.x, true);
    f32x2 a2 = __builtin_amdgcn_cvt_pk_f32_fp8(v.y, false);
    f32x2 a3 = __builtin_amdgcn_cvt_pk_f32_fp8(v.y, true);
    r[0] = a0[0]; r[1] = a0[1]; r[2] = a1[0]; r[3] = a1[1];
    r[4] = a2[0]; r[5] = a2[1]; r[6] = a3[0]; r[7] = a3[1];
}

template <int VEC>
__device__ inline void loadbf(const unsigned short* __restrict__ p, float (&r)[VEC]) {
    typename RawVec<VEC>::T v = *(const typename RawVec<VEC>::T*)p;
    unpackr(v, r);
}
template <int VEC>
__device__ inline void loadf32(const float* __restrict__ p, float (&r)[VEC]) {
    if constexpr (VEC == 2) {
        float2 t = *reinterpret_cast<const float2*>(p);
        r[0] = t.x; r[1] = t.y;
    } else {
#pragma unroll
        for (int i = 0; i < VEC; i += 4) {
            float4 t = *reinterpret_cast<const float4*>(p + i);
            r[i] = t.x; r[i + 1] = t.y; r[i + 2] = t.z; r[i + 3] = t.w;
        }
    }
}
template <int VEC>
__device__ inline void storebf(unsigned short* __restrict__ p, const float (&r)[VEC]) {
    unsigned w[VEC / 2];
#pragma unroll
    for (int i = 0; i < VEC / 2; i++)
        w[i] = (unsigned)f2bf(r[2 * i]) | ((unsigned)f2bf(r[2 * i + 1]) << 16);
    if constexpr (VEC == 2) *(unsigned*)p = w[0];
    else if constexpr (VEC == 4) *(uint2*)p = make_uint2(w[0], w[1]);
    else *(uint4*)p = make_uint4(w[0], w[1], w[2], w[3]);
}

// One wave per node. Q,S from bf16 QKVS; K,V gathered from packed fp8 KV8.
template <int H, int D, bool RELU>
__global__ __launch_bounds__(256) void aggregate_k(
    const unsigned short* __restrict__ QKVS, int SR,
    const unsigned char* __restrict__ KV8,
    const float* __restrict__ ew,
    const int* __restrict__ rowptr, const int* __restrict__ csrc,
    const float* __restrict__ cea, unsigned short* __restrict__ Hout) {
    constexpr int F = H * D;
    constexpr int VEC = F / 64;
    constexpr int L = 64 / H;
    using RawT = typename Raw8<VEC>::T;
    int lane = threadIdx.x & 63;
    int node = blockIdx.x * 4 + (threadIdx.x >> 6);
    if (node >= NN) return;

    const unsigned short* qrow = QKVS + (size_t)node * SR;
    float q[VEC], ewv[VEC], acc[VEC];
    loadbf<VEC>(qrow + lane * VEC, q);
    loadf32<VEC>(ew + lane * VEC, ewv);
#pragma unroll
    for (int i = 0; i < VEC; i++) acc[i] = 0.f;

    float den = 0.f;
    const float isd = rsqrtf((float)D);
    int beg = rowptr[node], end = rowptr[node + 1];

    for (int cb = beg; cb < end; cb += 64) {
        int cnt = min(end - cb, 64);
        int gi = cb + lane;
        int sidx = (gi < end) ? csrc[gi] : 0;        // coalesced: 64 indices
        float sea = (gi < end) ? cea[gi] : 0.f;      // coalesced: 64 edge attrs

        RawT k0r, k1r, k2r, k3r, v0r, v1r, v2r, v3r;
        float e0 = 0.f, e1 = 0.f, e2 = 0.f, e3 = 0.f;
        auto fetch = [&](int t, RawT& kr, RawT& vr, float& ea) {
            int s = __shfl(sidx, t, 64);
            ea = __shfl(sea, t, 64);
            const unsigned char* b = KV8 + (size_t)s * (2 * F) + lane * VEC;
            kr = *(const RawT*)b;
            vr = *(const RawT*)(b + F);
        };
        auto process = [&](RawT kr, RawT vr, float ea) {
            float kv[VEC], vv[VEC], t[VEC];
            unpackf8(kr, kv);
            unpackf8(vr, vv);
            float p = 0.f;
#pragma unroll
            for (int i = 0; i < VEC; i++) { t[i] = ea * ewv[i]; p += q[i] * (kv[i] + t[i]); }
#pragma unroll
            for (int off = 1; off < L; off <<= 1) p += __shfl_xor(p, off, 64);
            float w = __expf(fminf(p * isd, 30.f));
            den += w;
#pragma unroll
            for (int i = 0; i < VEC; i++) acc[i] += w * (vv[i] + t[i]);
        };

        if (cnt > 0) fetch(0, k0r, v0r, e0);
        if (cnt > 1) fetch(1, k1r, v1r, e1);
        if (cnt > 2) fetch(2, k2r, v2r, e2);
        if (cnt > 3) fetch(3, k3r, v3r, e3);

        for (int t = 0; t < cnt; t += 4) {
            process(k0r, v0r, e0);
            if (t + 4 < cnt) fetch(t + 4, k0r, v0r, e0);
            if (t + 1 < cnt) {
                process(k1r, v1r, e1);
                if (t + 5 < cnt) fetch(t + 5, k1r, v1r, e1);
            }
            if (t + 2 < cnt) {
                process(k2r, v2r, e2);
                if (t + 6 < cnt) fetch(t + 6, k2r, v2r, e2);
            }
            if (t + 3 < cnt) {
                process(k3r, v3r, e3);
                if (t + 7 < cnt) fetch(t + 7, k3r, v3r, e3);
            }
        }
    }

    float rden = (den > 0.f) ? 1.f / den : 0.f;
    float sv[VEC];
    loadbf<VEC>(qrow + 3 * F + lane * VEC, sv);
    float o[VEC];
#pragma unroll
    for (int i = 0; i < VEC; i++) {
        float v = acc[i] * rden + sv[i];
        o[i] = RELU ? fmaxf(v, 0.f) : v;
    }
    storebf<VEC>(Hout + (size_t)node * F + lane * VEC, o);
}

// ---------------------------------------------------------------- pool+head (fused)
__global__ __launch_bounds__(256) void pool_head_k(
    const unsigned short* __restrict__ h3, const int* __restrict__ gstart,
    const float* __restrict__ lw, const float* __restrict__ lb,
    float* __restrict__ out) {
    __shared__ float part[256];
    __shared__ float pooled[128];
    int g = blockIdx.x;
    int beg = gstart[g], end = gstart[g + 1];
    int d = threadIdx.x & 127, half = threadIdx.x >> 7;
    float s = 0.f;
    for (int node = beg + half; node < end; node += 2)
        s += bf2f(h3[(size_t)node * 128 + d]);
    part[threadIdx.x] = s;
    __syncthreads();
    if (threadIdx.x < 128) {
        float cnt = fmaxf((float)(end - beg), 1.0f);
        pooled[threadIdx.x] = (part[threadIdx.x] + part[threadIdx.x + 128]) / cnt;
    }
    __syncthreads();
    if (threadIdx.x < 13) {
        float acc = lb[threadIdx.x];
        for (int dd = 0; dd < 128; ++dd)
            acc += pooled[dd] * lw[dd * 13 + threadIdx.x];
        out[g * 13 + threadIdx.x] = acc;
    }
}

__global__ void ws_fail_k(float* __restrict__ out, int n) {
    int i = blockIdx.x * 256 + threadIdx.x;
    if (i < n) out[i] = -12345.0f;
}

// ---------------------------------------------------------------- launch
extern "C" void kernel_launch(void* const* d_in, const int* in_sizes, int n_in,
                              void* d_out, int out_size, void* d_ws, size_t ws_size,
                              hipStream_t stream) {
    const float* x   = (const float*)d_in[0];
    const int*   ei  = (const int*)d_in[1];
    const float* ea  = (const float*)d_in[2];
    const int*   bat = (const int*)d_in[3];
    const float* W1[4] = {(const float*)d_in[4], (const float*)d_in[6], (const float*)d_in[8], (const float*)d_in[11]};
    const float* B1[4] = {(const float*)d_in[5], (const float*)d_in[7], (const float*)d_in[9], (const float*)d_in[12]};
    const float* e1w = (const float*)d_in[10];
    const float* W2[4] = {(const float*)d_in[13], (const float*)d_in[15], (const float*)d_in[17], (const float*)d_in[20]};
    const float* B2[4] = {(const float*)d_in[14], (const float*)d_in[16], (const float*)d_in[18], (const float*)d_in[21]};
    const float* e2w = (const float*)d_in[19];
    const float* W3[4] = {(const float*)d_in[22], (const float*)d_in[24], (const float*)d_in[26], (const float*)d_in[29]};
    const float* B3[4] = {(const float*)d_in[23], (const float*)d_in[25], (const float*)d_in[27], (const float*)d_in[30]};
    const float* e3w = (const float*)d_in[28];
    const float* lw  = (const float*)d_in[31];
    const float* lb  = (const float*)d_in[32];

    char* wsb = (char*)d_ws;
    size_t off = 0;
    auto alloc_b = [&](size_t bytes) {
        void* p = wsb + off;
        off += (bytes + 255) & ~(size_t)255;
        return p;
    };
    unsigned short* xb   = (unsigned short*)alloc_b((size_t)NN * 256 * 2);
    unsigned short* Wc1  = (unsigned short*)alloc_b((size_t)2048 * 256 * 2);
    float*          bc1  = (float*)alloc_b(2048 * 4);
    unsigned short* Wc2  = (unsigned short*)alloc_b((size_t)1024 * 512 * 2);
    float*          bc2  = (float*)alloc_b(1024 * 4);
    unsigned short* Wc3  = (unsigned short*)alloc_b((size_t)512 * 256 * 2);
    float*          bc3  = (float*)alloc_b(512 * 4);
    unsigned short* QKVS = (unsigned short*)alloc_b((size_t)NN * 2048 * 2);
    unsigned char*  KV8  = (unsigned char*)alloc_b((size_t)NN * 1024);   // max 2F = 1024 bytes/row
    unsigned short* H1   = (unsigned short*)alloc_b((size_t)NN * 512 * 2);
    unsigned short* H2   = (unsigned short*)alloc_b((size_t)NN * 256 * 2);
    unsigned short* H3   = (unsigned short*)alloc_b((size_t)NN * 128 * 2);
    int*   basep  = (int*)alloc_b((NN + 1) * 4);
    int*   csrc   = (int*)alloc_b((size_t)EE * 4);
    float* cea    = (float*)alloc_b((size_t)EE * 4);
    int*   gstart = (int*)alloc_b((GG + 1) * 4);
    size_t zstart = off;
    int*   deg    = (int*)alloc_b(NN * 4);
    int*   cnt    = (int*)alloc_b(NN * 4);
    size_t zbytes = off - zstart;

    if (ws_size < off) {
        ws_fail_k<<<(out_size + 255) / 256, 256, 0, stream>>>((float*)d_out, out_size);
        return;
    }

    hipMemsetAsync(wsb + zstart, 0, zbytes, stream);

    PrepArgs pa;
    int blk = 0, di = 0;
    auto add = [&](const float* src, void* dst, int rows, int cols, int mode) {
        pa.d[di].src = src; pa.d[di].dst = dst;
        pa.d[di].rows = rows; pa.d[di].cols = cols;
        pa.d[di].mode = mode; pa.d[di].blk0 = blk;
        blk += (rows * cols + 1023) / 1024;
        di++;
    };
    add(x, xb, NN * 256, 1, 0);
    for (int s = 0; s < 4; s++) add(W1[s], Wc1 + (size_t)s * 512 * 256, 256, 512, 1);
    for (int s = 0; s < 4; s++) add(B1[s], bc1 + s * 512, 512, 1, 2);
    for (int s = 0; s < 4; s++) add(W2[s], Wc2 + (size_t)s * 256 * 512, 512, 256, 1);
    for (int s = 0; s < 4; s++) add(B2[s], bc2 + s * 256, 256, 1, 2);
    for (int s = 0; s < 4; s++) add(W3[s], Wc3 + (size_t)s * 128 * 256, 256, 128, 1);
    for (int s = 0; s < 4; s++) add(B3[s], bc3 + s * 128, 128, 1, 2);
    prep_k<<<blk, 256, 0, stream>>>(pa);

    int eblocks = (EE + 255) / 256;
    count_deg_k<<<eblocks, 256, 0, stream>>>(ei, deg);
    scan_excl_k<<<1, 1024, 0, stream>>>(deg, basep);
    fill_csr_k<<<eblocks, 256, 0, stream>>>(ei, ea, basep, cnt, csrc, cea);
    gbound_k<<<(NN + 255) / 256, 256, 0, stream>>>(bat, gstart);

    int mblocks = (NN + 127) / 128;
    // ---- layer 1: x[30000,256] -> QKVS[30000,2048] (+ fused fp8 K|V pack)
    gemm_bf16_k<<<dim3(2048 / 128, mblocks), 256, 0, stream>>>(xb, Wc1, bc1, QKVS, KV8, NN, 256, 2048);
    aggregate_k<8, 64, true><<<NN / 4, 256, 0, stream>>>(QKVS, 2048, KV8, e1w, basep, csrc, cea, H1);
    // ---- layer 2: H1[30000,512] -> QKVS[30000,1024]
    gemm_bf16_k<<<dim3(1024 / 128, mblocks), 256, 0, stream>>>(H1, Wc2, bc2, QKVS, KV8, NN, 512, 1024);
    aggregate_k<4, 64, true><<<NN / 4, 256, 0, stream>>>(QKVS, 1024, KV8, e2w, basep, csrc, cea, H2);
    // ---- layer 3: H2[30000,256] -> QKVS[30000,512]
    gemm_bf16_k<<<dim3(512 / 128, mblocks), 256, 0, stream>>>(H2, Wc3, bc3, QKVS, KV8, NN, 256, 512);
    aggregate_k<1, 128, false><<<NN / 4, 256, 0, stream>>>(QKVS, 512, KV8, e3w, basep, csrc, cea, H3);

    // ---- fused pool + head
    pool_head_k<<<GG, 256, 0, stream>>>(H3, gstart, lw, lb, (float*)d_out);
}